// Round 9
// baseline (149.222 us; speedup 1.0000x reference)
//
#include <hip/hip_runtime.h>
#include <hip/hip_bf16.h>

// ---- problem constants ----
constexpr int N0 = 400000, N1 = 75000, N2 = 15000;
constexpr int E1 = 1200000, E2 = 240000;
constexpr int NC = 40;
constexpr float NEG_SLOPE = 0.2f;

// two-level binning: coarse buckets amortize global atomics over edge chunks
constexpr int BK1 = 128;                     // dst nodes per bucket, layer 1
constexpr int NB1 = (N1 + BK1 - 1) / BK1;    // 586
constexpr int CAPB1 = 2432;                  // mean 2048, sd ~45 -> +8.5 sigma
constexpr int BK2 = 32;                      // dst nodes per bucket, layer 2
constexpr int NB2 = (N2 + BK2 - 1) / BK2;    // 469
constexpr int CAPB2 = 704;                   // mean 512, sd ~23 -> +8.5 sigma

constexpr int TILE = 8192;                   // edges per binning block
constexpr int NT1 = (E1 + TILE - 1) / TILE;  // 147
constexpr int NT2 = (E2 + TILE - 1) / TILE;  // 30
constexpr int BPJ = (N0 + 255) / 256;        // 1563 projection blocks (256 nodes each)

__device__ __forceinline__ float leaky(float v) { return v > 0.f ? v : NEG_SLOPE * v; }

// RNE pack of two floats into a bf16x2 word
__device__ __forceinline__ unsigned bf16pair(float lo, float hi) {
    unsigned a = __float_as_uint(lo), b = __float_as_uint(hi);
    a = (a + 0x7FFFu + ((a >> 16) & 1u)) >> 16;
    b = (b + 0x7FFFu + ((b >> 16) & 1u)) & 0xFFFF0000u;
    return a | b;
}
__device__ __forceinline__ float bfLo(unsigned w) { return __uint_as_float(w << 16); }
__device__ __forceinline__ float bfHi(unsigned w) { return __uint_as_float(w & 0xFFFF0000u); }

// ============ K1: binning (first) + wave-cooperative projection (16 lanes/node) ============
// rec1[node] (16 words, 64B): w0..w7 bf16x2 hs1, w8/w9 fp32 a_s; w10..15 pad (full-line store)
__global__ __launch_bounds__(256) void k1_kernel(
    const float* __restrict__ x,
    const float* __restrict__ W1s, const float* __restrict__ W1d,
    const float* __restrict__ att1s, const float* __restrict__ att1d,
    const int* __restrict__ e1s, const int* __restrict__ e1d,
    const int* __restrict__ e2s, const int* __restrict__ e2d,
    unsigned* __restrict__ rec1, float* __restrict__ a_d1,
    int* __restrict__ gcnt1, unsigned* __restrict__ bin1,
    int* __restrict__ gcnt2, unsigned* __restrict__ bin2)
{
    __shared__ int hist[NB1];      // NB1 >= NB2; only binning blocks touch LDS
    __shared__ int gbase[NB1];

    int bid = blockIdx.x;
    const int tid = threadIdx.x;
    if (bid < NT1 + NT2) {
        // ---- binning tiles (scheduled first; overlap with projection tail) ----
        const bool isL1 = bid < NT1;
        const int* es = isL1 ? e1s : e2s;
        const int* ed = isL1 ? e1d : e2d;
        const int nE = isL1 ? E1 : E2;
        const int nb = isL1 ? NB1 : NB2;
        const int cap = isL1 ? CAPB1 : CAPB2;
        const int shift = isL1 ? 7 : 5;       // log2(BK)
        const int lsh = isL1 ? 19 : 17;       // local-dst shift in payload
        int* gc = isL1 ? gcnt1 : gcnt2;
        unsigned* gbin = isL1 ? bin1 : bin2;
        const int base = (isL1 ? bid : bid - NT1) * TILE;
        const int lim = min(TILE, nE - base);

        for (int b = tid; b < nb; b += 256) hist[b] = 0;
        __syncthreads();
        for (int i = tid; i < lim; i += 256) {
            int s = es[base + i], d = ed[base + i];
            if (s != d) atomicAdd(&hist[d >> shift], 1);   // remove_self_loops
        }
        __syncthreads();
        for (int b = tid; b < nb; b += 256) {
            int c = hist[b];
            gbase[b] = (c > 0) ? atomicAdd(&gc[b], c) : 0; // ONE global atomic per chunk
            hist[b] = 0;                                   // reuse as cursor
        }
        __syncthreads();
        for (int i = tid; i < lim; i += 256) {
            int s = es[base + i], d = ed[base + i];
            if (s != d) {
                int b = d >> shift;
                int pos = gbase[b] + atomicAdd(&hist[b], 1);
                if (pos < cap)
                    gbin[(size_t)b * cap + pos] =
                        (unsigned)s | ((unsigned)(d & ((1 << shift) - 1)) << lsh);
            }
        }
        return;
    }
    // ---- projection: 16 lanes per node; W rows register-resident per lane ----
    bid -= NT1 + NT2;
    const int g = tid >> 4;          // group 0..15 (one node at a time)
    const int c = tid & 15;          // lane within group = channel id
    const int wbase = tid & 48;      // group base lane within the 64-lane wave

    // W1s rows 4c..4c+3 into registers (reused for 256 nodes)
    float Wr[4][16];
    {
        const float4* Wv4 = (const float4*)W1s;
        #pragma unroll
        for (int r = 0; r < 4; ++r)
            #pragma unroll
            for (int q = 0; q < 4; ++q) {
                float4 t = Wv4[(4 * c + r) * 4 + q];
                Wr[r][4 * q + 0] = t.x; Wr[r][4 * q + 1] = t.y;
                Wr[r][4 * q + 2] = t.z; Wr[r][4 * q + 3] = t.w;
            }
    }
    // vd rows: fold att1d into W1d rows 4c..4c+3 (per head)
    float vd0[4], vd1[4];
    #pragma unroll
    for (int r = 0; r < 4; ++r) {
        const float* wrow = W1d + (4 * c + r) * 16;
        float d0 = 0.f, d1 = 0.f;
        #pragma unroll
        for (int cc = 0; cc < 8; ++cc) {
            d0 = fmaf(wrow[cc], att1d[cc], d0);
            d1 = fmaf(wrow[8 + cc], att1d[8 + cc], d1);
        }
        vd0[r] = d0; vd1[r] = d1;
    }
    const float attv = att1s[c];
    const int nodeBase = bid * 256;

    for (int it = 0; it < 16; ++it) {
        const int node = nodeBase + it * 16 + g;
        if (node >= N0) break;
        // one fully-coalesced 1KB wave-load: lane c reads float4 #c of the row
        float4 xv = ((const float4*)(x + (size_t)node * 64))[c];
        float xk[4] = {xv.x, xv.y, xv.z, xv.w};

        // 16 channel-partials from this lane's 4 x values
        float s[16];
        #pragma unroll
        for (int cc = 0; cc < 16; ++cc) {
            float v = xk[0] * Wr[0][cc];
            v = fmaf(xk[1], Wr[1][cc], v);
            v = fmaf(xk[2], Wr[2][cc], v);
            v = fmaf(xk[3], Wr[3][cc], v);
            s[cc] = v;
        }
        // select-butterfly reduce: lane c ends with ss[channel c]
        {
            float t[16];
            #pragma unroll
            for (int j = 0; j < 16; ++j) t[j] = __shfl_xor(s[j], 8, 64);
            const bool hi8 = (c & 8);
            #pragma unroll
            for (int j = 0; j < 8; ++j) s[j] = hi8 ? (s[j + 8] + t[j + 8]) : (s[j] + t[j]);
            #pragma unroll
            for (int j = 0; j < 8; ++j) t[j] = __shfl_xor(s[j], 4, 64);
            const bool hi4 = (c & 4);
            #pragma unroll
            for (int j = 0; j < 4; ++j) s[j] = hi4 ? (s[j + 4] + t[j + 4]) : (s[j] + t[j]);
            #pragma unroll
            for (int j = 0; j < 4; ++j) t[j] = __shfl_xor(s[j], 2, 64);
            const bool hi2 = (c & 2);
            #pragma unroll
            for (int j = 0; j < 2; ++j) s[j] = hi2 ? (s[j + 2] + t[j + 2]) : (s[j] + t[j]);
            t[0] = __shfl_xor(s[0], 1, 64);
            t[1] = __shfl_xor(s[1], 1, 64);
            s[0] = (c & 1) ? (s[1] + t[1]) : (s[0] + t[0]);
        }
        const float ssc = s[0];                       // = ss[c]

        // a_s per head: sum ss[c]*att1s[c] over each 8-lane half
        float p = ssc * attv;
        p += __shfl_xor(p, 1, 64);
        p += __shfl_xor(p, 2, 64);
        p += __shfl_xor(p, 4, 64);                    // lanes0-7: head0, lanes8-15: head1

        // pack + store: lane c writes word c of the 64B record
        float lo = __shfl(ssc, wbase + ((2 * c) & 15), 64);
        float hi = __shfl(ssc, wbase + ((2 * c + 1) & 15), 64);
        float pa0 = __shfl(p, wbase, 64);
        float pa1 = __shfl(p, wbase + 8, 64);
        unsigned w;
        if (c < 8)       w = bf16pair(lo, hi);
        else if (c == 8) w = __float_as_uint(pa0);
        else if (c == 9) w = __float_as_uint(pa1);
        else             w = 0u;
        rec1[(size_t)node * 16 + c] = w;

        if (node < N1) {                              // a_d1 = x . vd (folded)
            float pd0 = xk[0] * vd0[0], pd1 = xk[0] * vd1[0];
            #pragma unroll
            for (int r = 1; r < 4; ++r) {
                pd0 = fmaf(xk[r], vd0[r], pd0);
                pd1 = fmaf(xk[r], vd1[r], pd1);
            }
            #pragma unroll
            for (int k = 1; k < 16; k <<= 1) {
                pd0 += __shfl_xor(pd0, k, 64);
                pd1 += __shfl_xor(pd1, k, 64);
            }
            if (c == 0) ((float2*)a_d1)[node] = make_float2(pd0, pd1);
        }
    }
}

// ============ K2: layer-1 bucket sort + node-major aggregate + fused proj2 ============
// rec2[node] (24 words, 96B): w0..w19 bf16x2 hs2, w20 a_s2, w21 a_d2
__global__ __launch_bounds__(512) void k2_kernel(
    const int* __restrict__ gcnt1, const unsigned* __restrict__ bin1,
    const unsigned* __restrict__ rec1, const float* __restrict__ a_d1,
    const float* __restrict__ b1,
    const float* __restrict__ W2s, const float* __restrict__ W2d,
    const float* __restrict__ att2s, const float* __restrict__ att2d,
    unsigned* __restrict__ rec2)
{
    __shared__ unsigned srt[CAPB1];
    __shared__ int hist[BK1], start[BK1 + 1];
    __shared__ float w2sl[640], va[16], vd[16];
    __shared__ float h1s[BK1][17];

    const int b = blockIdx.x, tid = threadIdx.x;
    const int d0 = b * BK1;
    const int nN = min(BK1, N1 - d0);
    const int ncnt = min(gcnt1[b], CAPB1);
    const unsigned* bp = bin1 + (size_t)b * CAPB1;

    for (int i = tid; i < 640; i += 512) w2sl[i] = W2s[i];
    if (tid < BK1) hist[tid] = 0;
    if (tid >= 128 && tid < 144) {            // fold att2 into W2 columns
        int k = tid - 128;
        float sa = 0.f, sd = 0.f;
        for (int cc = 0; cc < 40; ++cc) {
            sa = fmaf(W2s[k * 40 + cc], att2s[cc], sa);
            sd = fmaf(W2d[k * 40 + cc], att2d[cc], sd);
        }
        va[k] = sa; vd[k] = sd;
    }
    __syncthreads();
    for (int i = tid; i < ncnt; i += 512) atomicAdd(&hist[bp[i] >> 19], 1);
    __syncthreads();
    if (tid == 0) {
        int a = 0;
        for (int k = 0; k < BK1; ++k) { start[k] = a; a += hist[k]; }
        start[BK1] = a;
    }
    __syncthreads();
    if (tid < BK1) hist[tid] = start[tid];    // cursor
    __syncthreads();
    for (int i = tid; i < ncnt; i += 512) {
        unsigned p = bp[i];
        int pos = atomicAdd(&hist[p >> 19], 1);
        srt[pos] = p & 0x7FFFFu;
    }
    __syncthreads();

    // node-major aggregation: 32 groups of 16 lanes, 4-deep prefetch
    const int g = tid >> 4, c = tid & 15, h = c >> 3;
    const int wbase = tid & 48;
    const int wmap = (c < 8) ? c : (8 + ((c >> 2) & 1));
    for (int n = g; n < nN; n += 32) {
        const int node = d0 + n;
        const float ad = a_d1[(size_t)node * 2 + h];
        const int st = start[n], cnt = start[n + 1] - start[n];
        // source j: 0 = self, 1..cnt = srt[st+j-1]
        unsigned rw0 = rec1[(size_t)node * 16 + wmap];
        unsigned rw1 = (cnt >= 1) ? rec1[(size_t)srt[st] * 16 + wmap] : 0u;
        unsigned rw2 = (cnt >= 2) ? rec1[(size_t)srt[st + 1] * 16 + wmap] : 0u;
        unsigned rw3 = (cnt >= 3) ? rec1[(size_t)srt[st + 2] * 16 + wmap] : 0u;
        float accv = 0.f, den = 0.f;
        for (int j = 0; j <= cnt; ++j) {
            float asv = __uint_as_float((unsigned)__shfl((int)rw0, wbase + 8 + 4 * h, 64));
            unsigned chw = (unsigned)__shfl((int)rw0, wbase + (c >> 1), 64);
            float hv = (c & 1) ? bfHi(chw) : bfLo(chw);
            float w = __expf(leaky(asv + ad));
            accv = fmaf(w, hv, accv);
            den += w;
            rw0 = rw1; rw1 = rw2; rw2 = rw3;
            rw3 = (j + 4 <= cnt) ? rec1[(size_t)srt[st + j + 3] * 16 + wmap] : 0u;
        }
        float v = accv / den + b1[c];
        h1s[n][c] = v > 0.f ? v : (__expf(v) - 1.f);    // ELU
    }
    __syncthreads();
    // fused proj2 -> rec2
    for (int i = tid; i < nN * 24; i += 512) {
        int nn = i / 24, w = i - nn * 24;
        unsigned* rp = rec2 + (size_t)(d0 + nn) * 24;
        if (w < 20) {
            int c0 = 2 * w, c1 = c0 + 1;
            float s0 = 0.f, s1 = 0.f;
            #pragma unroll
            for (int k = 0; k < 16; ++k) {
                float hk = h1s[nn][k];
                s0 = fmaf(hk, w2sl[k * 40 + c0], s0);
                s1 = fmaf(hk, w2sl[k * 40 + c1], s1);
            }
            rp[w] = bf16pair(s0, s1);
        } else if (w < 22) {
            const float* vv = (w == 20) ? va : vd;
            float s = 0.f;
            #pragma unroll
            for (int k = 0; k < 16; ++k) s = fmaf(h1s[nn][k], vv[k], s);
            rp[w] = __float_as_uint(s);
        }
    }
}

// ============ K3: layer-2 bucket sort + 32-lane-group aggregate + log_softmax ============
__global__ __launch_bounds__(1024) void k3_kernel(
    const int* __restrict__ gcnt2, const unsigned* __restrict__ bin2,
    const unsigned* __restrict__ rec2, const float* __restrict__ b2,
    float* __restrict__ out)
{
    __shared__ unsigned srt[CAPB2];
    __shared__ int hist[BK2], start[BK2 + 1];

    const int b = blockIdx.x, tid = threadIdx.x;
    const int d0 = b * BK2;
    const int nN = min(BK2, N2 - d0);
    const int ncnt = min(gcnt2[b], CAPB2);
    const unsigned* bp = bin2 + (size_t)b * CAPB2;

    if (tid < BK2) hist[tid] = 0;
    __syncthreads();
    for (int i = tid; i < ncnt; i += 1024) atomicAdd(&hist[bp[i] >> 17], 1);
    __syncthreads();
    if (tid == 0) {
        int a = 0;
        for (int k = 0; k < BK2; ++k) { start[k] = a; a += hist[k]; }
        start[BK2] = a;
    }
    __syncthreads();
    if (tid < BK2) hist[tid] = start[tid];
    __syncthreads();
    for (int i = tid; i < ncnt; i += 1024) {
        unsigned p = bp[i];
        int pos = atomicAdd(&hist[p >> 17], 1);
        srt[pos] = p & 0x1FFFFu;
    }
    __syncthreads();

    // 32 groups of 32 lanes; lane l holds record word l (channels 2l,2l+1 for l<20)
    const int g = tid >> 5, l = tid & 31;
    const float bb0 = (l < 20) ? b2[2 * l] : 0.f;
    const float bb1 = (l < 20) ? b2[2 * l + 1] : 0.f;
    for (int n = g; n < nN; n += 32) {
        const int node = d0 + n;
        const int st = start[n], cnt = start[n + 1] - start[n];
        unsigned rw0 = (l < 22) ? rec2[(size_t)node * 24 + l] : 0u;          // self
        const float ad = __uint_as_float((unsigned)__shfl((int)rw0, 21, 32));
        unsigned rw1 = (cnt >= 1 && l < 21) ? rec2[(size_t)srt[st] * 24 + l] : 0u;
        unsigned rw2 = (cnt >= 2 && l < 21) ? rec2[(size_t)srt[st + 1] * 24 + l] : 0u;
        unsigned rw3 = (cnt >= 3 && l < 21) ? rec2[(size_t)srt[st + 2] * 24 + l] : 0u;
        float a0 = 0.f, a1 = 0.f, den = 0.f;
        for (int j = 0; j <= cnt; ++j) {
            float asv = __uint_as_float((unsigned)__shfl((int)rw0, 20, 32));
            float w = __expf(leaky(asv + ad));
            a0 = fmaf(w, bfLo(rw0), a0);
            a1 = fmaf(w, bfHi(rw0), a1);
            den += w;
            rw0 = rw1; rw1 = rw2; rw2 = rw3;
            rw3 = (j + 4 <= cnt && l < 21) ? rec2[(size_t)srt[st + j + 3] * 24 + l] : 0u;
        }
        float v0 = (l < 20) ? a0 / den + bb0 : -3.4e38f;
        float v1 = (l < 20) ? a1 / den + bb1 : -3.4e38f;
        float mx = fmaxf(v0, v1);
        #pragma unroll
        for (int k = 16; k >= 1; k >>= 1) mx = fmaxf(mx, __shfl_xor(mx, k, 32));
        float ex = (l < 20) ? __expf(v0 - mx) + __expf(v1 - mx) : 0.f;
        #pragma unroll
        for (int k = 16; k >= 1; k >>= 1) ex += __shfl_xor(ex, k, 32);
        float lse = mx + logf(ex);
        if (l < 20)
            ((float2*)(out + (size_t)node * 40))[l] = make_float2(v0 - lse, v1 - lse);
    }
}

extern "C" void kernel_launch(void* const* d_in, const int* in_sizes, int n_in,
                              void* d_out, int out_size, void* d_ws, size_t ws_size,
                              hipStream_t stream) {
    const float* x      = (const float*)d_in[0];
    const int*   e1_src = (const int*)d_in[1];
    const int*   e1_dst = (const int*)d_in[2];
    const int*   e2_src = (const int*)d_in[3];
    const int*   e2_dst = (const int*)d_in[4];
    const float* W1s    = (const float*)d_in[5];
    const float* W1d    = (const float*)d_in[6];
    const float* att1s  = (const float*)d_in[7];
    const float* att1d  = (const float*)d_in[8];
    const float* b1     = (const float*)d_in[9];
    const float* W2s    = (const float*)d_in[10];
    const float* W2d    = (const float*)d_in[11];
    const float* att2s  = (const float*)d_in[12];
    const float* att2d  = (const float*)d_in[13];
    const float* b2     = (const float*)d_in[14];
    float* out = (float*)d_out;

    // ---- workspace layout (4-byte words) ----
    float* wsbase = (float*)d_ws;
    size_t o = 0;
    int*      gcnt1 = (int*)(wsbase + o);      o += NB1;
    int*      gcnt2 = (int*)(wsbase + o);      o += NB2;
    const size_t zeroWords = o;                // only counters need zeroing
    unsigned* bin1  = (unsigned*)(wsbase + o); o += (size_t)NB1 * CAPB1;
    unsigned* bin2  = (unsigned*)(wsbase + o); o += (size_t)NB2 * CAPB2;
    unsigned* rec1  = (unsigned*)(wsbase + o); o += (size_t)N0 * 16;
    float*    a_d1  = (float*)(wsbase + o);    o += (size_t)N1 * 2;
    unsigned* rec2  = (unsigned*)(wsbase + o); o += (size_t)N1 * 24;

    hipMemsetAsync(d_ws, 0, zeroWords * sizeof(float), stream);

    k1_kernel<<<NT1 + NT2 + BPJ, 256, 0, stream>>>(
        x, W1s, W1d, att1s, att1d, e1_src, e1_dst, e2_src, e2_dst,
        rec1, a_d1, gcnt1, bin1, gcnt2, bin2);

    k2_kernel<<<NB1, 512, 0, stream>>>(gcnt1, bin1, rec1, a_d1, b1,
                                       W2s, W2d, att2s, att2d, rec2);

    k3_kernel<<<NB2, 1024, 0, stream>>>(gcnt2, bin2, rec2, b2, out);
}

// Round 10
// 117.280 us; speedup vs baseline: 1.2724x; 1.2724x over previous
//
#include <hip/hip_runtime.h>
#include <hip/hip_bf16.h>

// ---- problem constants ----
constexpr int N0 = 400000, N1 = 75000, N2 = 15000;
constexpr int E1 = 1200000, E2 = 240000;
constexpr int NC = 40;
constexpr float NEG_SLOPE = 0.2f;

// two-level binning: coarse buckets amortize global atomics over edge chunks
constexpr int BK1 = 128;                     // dst nodes per bucket, layer 1
constexpr int NB1 = (N1 + BK1 - 1) / BK1;    // 586
constexpr int CAPB1 = 2432;                  // mean 2048, sd ~45 -> +8.5 sigma
constexpr int BK2 = 32;                      // dst nodes per bucket, layer 2
constexpr int NB2 = (N2 + BK2 - 1) / BK2;    // 469
constexpr int CAPB2 = 704;                   // mean 512, sd ~23 -> +8.5 sigma

constexpr int TILE = 8192;                   // edges per binning block
constexpr int NT1 = (E1 + TILE - 1) / TILE;  // 147
constexpr int NT2 = (E2 + TILE - 1) / TILE;  // 30
constexpr int BPJ = (N0 + 255) / 256;        // 1563 projection blocks (256 nodes each)

using f32x4 = __attribute__((ext_vector_type(4))) float;
using s16x8 = __attribute__((ext_vector_type(8))) short;   // 8 bf16 (4 VGPRs)

__device__ __forceinline__ float leaky(float v) { return v > 0.f ? v : NEG_SLOPE * v; }

// v_cvt_pk_bf16_f32: D[15:0]=bf16(lo), D[31:16]=bf16(hi) (no builtin on gfx950)
__device__ __forceinline__ unsigned cvtpk(float lo, float hi) {
    unsigned r;
    asm("v_cvt_pk_bf16_f32 %0, %1, %2" : "=v"(r) : "v"(lo), "v"(hi));
    return r;
}

// RNE pack of two floats into a bf16x2 word (VALU fallback, used cold paths)
__device__ __forceinline__ unsigned bf16pair(float lo, float hi) {
    unsigned a = __float_as_uint(lo), b = __float_as_uint(hi);
    a = (a + 0x7FFFu + ((a >> 16) & 1u)) >> 16;
    b = (b + 0x7FFFu + ((b >> 16) & 1u)) & 0xFFFF0000u;
    return a | b;
}
__device__ __forceinline__ float bfLo(unsigned w) { return __uint_as_float(w << 16); }
__device__ __forceinline__ float bfHi(unsigned w) { return __uint_as_float(w & 0xFFFF0000u); }

// ============ K1: binning (first) + MFMA projection (16 nodes / wave-iter) ============
// rec1[node] (16 words, 64B): w0..w7 bf16x2 hs1, w8/w9 fp32 a_s; w10..15 pad
__global__ __launch_bounds__(256) void k1_kernel(
    const float* __restrict__ x,
    const float* __restrict__ W1s, const float* __restrict__ W1d,
    const float* __restrict__ att1s, const float* __restrict__ att1d,
    const int* __restrict__ e1s, const int* __restrict__ e1d,
    const int* __restrict__ e2s, const int* __restrict__ e2d,
    unsigned* __restrict__ rec1, float* __restrict__ a_d1,
    int* __restrict__ gcnt1, unsigned* __restrict__ bin1,
    int* __restrict__ gcnt2, unsigned* __restrict__ bin2)
{
    __shared__ int hist[NB1];                  // binning blocks only
    __shared__ int gbase[NB1];
    __shared__ float sstage[4][16][18];        // proj: per-wave 16x16 hs tile (+pad)
    __shared__ float sas[4][16][2];            // proj: per-wave a_s tile

    int bid = blockIdx.x;
    const int tid = threadIdx.x;
    if (bid < NT1 + NT2) {
        // ---- binning tiles ----
        const bool isL1 = bid < NT1;
        const int* es = isL1 ? e1s : e2s;
        const int* ed = isL1 ? e1d : e2d;
        const int nE = isL1 ? E1 : E2;
        const int nb = isL1 ? NB1 : NB2;
        const int cap = isL1 ? CAPB1 : CAPB2;
        const int shift = isL1 ? 7 : 5;        // log2(BK)
        const int lsh = isL1 ? 19 : 17;        // local-dst shift in payload
        int* gc = isL1 ? gcnt1 : gcnt2;
        unsigned* gbin = isL1 ? bin1 : bin2;
        const int base = (isL1 ? bid : bid - NT1) * TILE;
        const int lim = min(TILE, nE - base);

        for (int b = tid; b < nb; b += 256) hist[b] = 0;
        __syncthreads();
        for (int i = tid; i < lim; i += 256) {
            int s = es[base + i], d = ed[base + i];
            if (s != d) atomicAdd(&hist[d >> shift], 1);   // remove_self_loops
        }
        __syncthreads();
        for (int b = tid; b < nb; b += 256) {
            int c = hist[b];
            gbase[b] = (c > 0) ? atomicAdd(&gc[b], c) : 0; // ONE global atomic per chunk
            hist[b] = 0;                                   // reuse as cursor
        }
        __syncthreads();
        for (int i = tid; i < lim; i += 256) {
            int s = es[base + i], d = ed[base + i];
            if (s != d) {
                int b = d >> shift;
                int pos = gbase[b] + atomicAdd(&hist[b], 1);
                if (pos < cap)
                    gbin[(size_t)b * cap + pos] =
                        (unsigned)s | ((unsigned)(d & ((1 << shift) - 1)) << lsh);
            }
        }
        return;
    }
    // ---- MFMA projection ----
    bid -= NT1 + NT2;
    const int wv  = tid >> 6;        // wave 0..3
    const int l   = tid & 63;        // lane
    const int row = l & 15;          // A-row (node), B-col (channel)
    const int kg  = l >> 4;          // k-group 0..3
    const int nodeBase = bid * 256;

    // B fragments from W1s (chunks m: k = 32m + 8kg + j)
    s16x8 bf0, bf1;
    {
        union { unsigned u[4]; s16x8 v; } t0, t1;
        #pragma unroll
        for (int q = 0; q < 4; ++q) {
            t0.u[q] = cvtpk(W1s[(8 * kg + 2 * q) * 16 + row],
                            W1s[(8 * kg + 2 * q + 1) * 16 + row]);
            t1.u[q] = cvtpk(W1s[(32 + 8 * kg + 2 * q) * 16 + row],
                            W1s[(32 + 8 * kg + 2 * q + 1) * 16 + row]);
        }
        bf0 = t0.v; bf1 = t1.v;
    }
    // vd (att1d folded into W1d), this lane's 16 k values — only blocks touching N1
    float vdh0[16], vdh1[16];
    if (nodeBase < N1) {
        #pragma unroll
        for (int m = 0; m < 2; ++m)
            #pragma unroll
            for (int j = 0; j < 8; ++j) {
                const float* wr = W1d + (size_t)(32 * m + 8 * kg + j) * 16;
                float d0 = 0.f, d1 = 0.f;
                #pragma unroll
                for (int cc = 0; cc < 8; ++cc) {
                    d0 = fmaf(wr[cc], att1d[cc], d0);
                    d1 = fmaf(wr[8 + cc], att1d[8 + cc], d1);
                }
                vdh0[m * 8 + j] = d0; vdh1[m * 8 + j] = d1;
            }
    }
    const float attv = att1s[row];

    for (int rnd = 0; rnd < 4; ++rnd) {
        const int base16 = nodeBase + rnd * 64 + wv * 16;
        if (base16 < N0) {
            const float* xrow = x + (size_t)(base16 + row) * 64;
            float4 p0 = *(const float4*)(xrow + 8 * kg);
            float4 p1 = *(const float4*)(xrow + 8 * kg + 4);
            float4 p2 = *(const float4*)(xrow + 32 + 8 * kg);
            float4 p3 = *(const float4*)(xrow + 32 + 8 * kg + 4);

            union { unsigned u[4]; s16x8 v; } a0, a1;
            a0.u[0] = cvtpk(p0.x, p0.y); a0.u[1] = cvtpk(p0.z, p0.w);
            a0.u[2] = cvtpk(p1.x, p1.y); a0.u[3] = cvtpk(p1.z, p1.w);
            a1.u[0] = cvtpk(p2.x, p2.y); a1.u[1] = cvtpk(p2.z, p2.w);
            a1.u[2] = cvtpk(p3.x, p3.y); a1.u[3] = cvtpk(p3.z, p3.w);

            f32x4 acc = {0.f, 0.f, 0.f, 0.f};
            acc = __builtin_amdgcn_mfma_f32_16x16x32_bf16(a0.v, bf0, acc, 0, 0, 0);
            acc = __builtin_amdgcn_mfma_f32_16x16x32_bf16(a1.v, bf1, acc, 0, 0, 0);
            // D: lane holds node (kg*4+r), channel row

            // a_s: per node, per head (8-lane halves of each 16-lane group)
            #pragma unroll
            for (int r2 = 0; r2 < 4; ++r2) {
                float p = acc[r2] * attv;
                p += __shfl_xor(p, 1, 64);
                p += __shfl_xor(p, 2, 64);
                p += __shfl_xor(p, 4, 64);
                sstage[wv][kg * 4 + r2][row] = acc[r2];
                if (row == 0 || row == 8) sas[wv][kg * 4 + r2][row >> 3] = p;
            }
            // a_d1 = x . vd  (nodes < N1)
            if (base16 < N1) {
                float xv8[16] = {p0.x, p0.y, p0.z, p0.w, p1.x, p1.y, p1.z, p1.w,
                                 p2.x, p2.y, p2.z, p2.w, p3.x, p3.y, p3.z, p3.w};
                float d0 = 0.f, d1 = 0.f;
                #pragma unroll
                for (int j = 0; j < 16; ++j) {
                    d0 = fmaf(xv8[j], vdh0[j], d0);
                    d1 = fmaf(xv8[j], vdh1[j], d1);
                }
                d0 += __shfl_xor(d0, 16, 64); d0 += __shfl_xor(d0, 32, 64);
                d1 += __shfl_xor(d1, 16, 64); d1 += __shfl_xor(d1, 32, 64);
                const int node = base16 + row;
                if (l < 16 && node < N1)
                    ((float2*)a_d1)[node] = make_float2(d0, d1);
            }
        }
        __syncthreads();
        // epilogue: 64 nodes -> coalesced 64B-record stores
        const int rb = nodeBase + rnd * 64;
        if (rb < N0) {
            for (int idx = tid; idx < 1024; idx += 256) {
                int node = idx >> 4, c = idx & 15;
                int wvv = node >> 4, n16 = node & 15;
                unsigned w;
                if (c < 8)       w = cvtpk(sstage[wvv][n16][2 * c], sstage[wvv][n16][2 * c + 1]);
                else if (c == 8) w = __float_as_uint(sas[wvv][n16][0]);
                else if (c == 9) w = __float_as_uint(sas[wvv][n16][1]);
                else             w = 0u;
                rec1[(size_t)(rb + node) * 16 + c] = w;
            }
        }
        __syncthreads();
    }
}

// ============ K2: layer-1 bucket sort + node-major aggregate + fused proj2 ============
// rec2[node] (24 words, 96B): w0..w19 bf16x2 hs2, w20 a_s2, w21 a_d2
__global__ __launch_bounds__(512) void k2_kernel(
    const int* __restrict__ gcnt1, const unsigned* __restrict__ bin1,
    const unsigned* __restrict__ rec1, const float* __restrict__ a_d1,
    const float* __restrict__ b1,
    const float* __restrict__ W2s, const float* __restrict__ W2d,
    const float* __restrict__ att2s, const float* __restrict__ att2d,
    unsigned* __restrict__ rec2)
{
    __shared__ unsigned srt[CAPB1];
    __shared__ int hist[BK1], start[BK1 + 1];
    __shared__ float w2sl[640], va[16], vd[16];
    __shared__ float h1s[BK1][17];

    const int b = blockIdx.x, tid = threadIdx.x;
    const int d0 = b * BK1;
    const int nN = min(BK1, N1 - d0);
    const int ncnt = min(gcnt1[b], CAPB1);
    const unsigned* bp = bin1 + (size_t)b * CAPB1;

    for (int i = tid; i < 640; i += 512) w2sl[i] = W2s[i];
    if (tid < BK1) hist[tid] = 0;
    if (tid >= 128 && tid < 144) {            // fold att2 into W2 columns
        int k = tid - 128;
        float sa = 0.f, sd = 0.f;
        for (int cc = 0; cc < 40; ++cc) {
            sa = fmaf(W2s[k * 40 + cc], att2s[cc], sa);
            sd = fmaf(W2d[k * 40 + cc], att2d[cc], sd);
        }
        va[k] = sa; vd[k] = sd;
    }
    __syncthreads();
    for (int i = tid; i < ncnt; i += 512) atomicAdd(&hist[bp[i] >> 19], 1);
    __syncthreads();
    if (tid == 0) {
        int a = 0;
        for (int k = 0; k < BK1; ++k) { start[k] = a; a += hist[k]; }
        start[BK1] = a;
    }
    __syncthreads();
    if (tid < BK1) hist[tid] = start[tid];    // cursor
    __syncthreads();
    for (int i = tid; i < ncnt; i += 512) {
        unsigned p = bp[i];
        int pos = atomicAdd(&hist[p >> 19], 1);
        srt[pos] = p & 0x7FFFFu;
    }
    __syncthreads();

    // node-major aggregation: 32 groups of 16 lanes, 4-deep prefetch
    const int g = tid >> 4, c = tid & 15, h = c >> 3;
    const int wbase = tid & 48;
    const int wmap = (c < 8) ? c : (8 + ((c >> 2) & 1));
    for (int n = g; n < nN; n += 32) {
        const int node = d0 + n;
        const float ad = a_d1[(size_t)node * 2 + h];
        const int st = start[n], cnt = start[n + 1] - start[n];
        // source j: 0 = self, 1..cnt = srt[st+j-1]
        unsigned rw0 = rec1[(size_t)node * 16 + wmap];
        unsigned rw1 = (cnt >= 1) ? rec1[(size_t)srt[st] * 16 + wmap] : 0u;
        unsigned rw2 = (cnt >= 2) ? rec1[(size_t)srt[st + 1] * 16 + wmap] : 0u;
        unsigned rw3 = (cnt >= 3) ? rec1[(size_t)srt[st + 2] * 16 + wmap] : 0u;
        float accv = 0.f, den = 0.f;
        for (int j = 0; j <= cnt; ++j) {
            float asv = __uint_as_float((unsigned)__shfl((int)rw0, wbase + 8 + 4 * h, 64));
            unsigned chw = (unsigned)__shfl((int)rw0, wbase + (c >> 1), 64);
            float hv = (c & 1) ? bfHi(chw) : bfLo(chw);
            float w = __expf(leaky(asv + ad));
            accv = fmaf(w, hv, accv);
            den += w;
            rw0 = rw1; rw1 = rw2; rw2 = rw3;
            rw3 = (j + 4 <= cnt) ? rec1[(size_t)srt[st + j + 3] * 16 + wmap] : 0u;
        }
        float v = accv / den + b1[c];
        h1s[n][c] = v > 0.f ? v : (__expf(v) - 1.f);    // ELU
    }
    __syncthreads();
    // fused proj2 -> rec2
    for (int i = tid; i < nN * 24; i += 512) {
        int nn = i / 24, w = i - nn * 24;
        unsigned* rp = rec2 + (size_t)(d0 + nn) * 24;
        if (w < 20) {
            int c0 = 2 * w, c1 = c0 + 1;
            float s0 = 0.f, s1 = 0.f;
            #pragma unroll
            for (int k = 0; k < 16; ++k) {
                float hk = h1s[nn][k];
                s0 = fmaf(hk, w2sl[k * 40 + c0], s0);
                s1 = fmaf(hk, w2sl[k * 40 + c1], s1);
            }
            rp[w] = bf16pair(s0, s1);
        } else if (w < 22) {
            const float* vv = (w == 20) ? va : vd;
            float s = 0.f;
            #pragma unroll
            for (int k = 0; k < 16; ++k) s = fmaf(h1s[nn][k], vv[k], s);
            rp[w] = __float_as_uint(s);
        }
    }
}

// ============ K3: layer-2 bucket sort + 32-lane-group aggregate + log_softmax ============
__global__ __launch_bounds__(1024) void k3_kernel(
    const int* __restrict__ gcnt2, const unsigned* __restrict__ bin2,
    const unsigned* __restrict__ rec2, const float* __restrict__ b2,
    float* __restrict__ out)
{
    __shared__ unsigned srt[CAPB2];
    __shared__ int hist[BK2], start[BK2 + 1];

    const int b = blockIdx.x, tid = threadIdx.x;
    const int d0 = b * BK2;
    const int nN = min(BK2, N2 - d0);
    const int ncnt = min(gcnt2[b], CAPB2);
    const unsigned* bp = bin2 + (size_t)b * CAPB2;

    if (tid < BK2) hist[tid] = 0;
    __syncthreads();
    for (int i = tid; i < ncnt; i += 1024) atomicAdd(&hist[bp[i] >> 17], 1);
    __syncthreads();
    if (tid == 0) {
        int a = 0;
        for (int k = 0; k < BK2; ++k) { start[k] = a; a += hist[k]; }
        start[BK2] = a;
    }
    __syncthreads();
    if (tid < BK2) hist[tid] = start[tid];
    __syncthreads();
    for (int i = tid; i < ncnt; i += 1024) {
        unsigned p = bp[i];
        int pos = atomicAdd(&hist[p >> 17], 1);
        srt[pos] = p & 0x1FFFFu;
    }
    __syncthreads();

    // 32 groups of 32 lanes; lane l holds record word l (channels 2l,2l+1 for l<20)
    const int g = tid >> 5, l = tid & 31;
    const float bb0 = (l < 20) ? b2[2 * l] : 0.f;
    const float bb1 = (l < 20) ? b2[2 * l + 1] : 0.f;
    for (int n = g; n < nN; n += 32) {
        const int node = d0 + n;
        const int st = start[n], cnt = start[n + 1] - start[n];
        unsigned rw0 = (l < 22) ? rec2[(size_t)node * 24 + l] : 0u;          // self
        const float ad = __uint_as_float((unsigned)__shfl((int)rw0, 21, 32));
        unsigned rw1 = (cnt >= 1 && l < 21) ? rec2[(size_t)srt[st] * 24 + l] : 0u;
        unsigned rw2 = (cnt >= 2 && l < 21) ? rec2[(size_t)srt[st + 1] * 24 + l] : 0u;
        unsigned rw3 = (cnt >= 3 && l < 21) ? rec2[(size_t)srt[st + 2] * 24 + l] : 0u;
        float a0 = 0.f, a1 = 0.f, den = 0.f;
        for (int j = 0; j <= cnt; ++j) {
            float asv = __uint_as_float((unsigned)__shfl((int)rw0, 20, 32));
            float w = __expf(leaky(asv + ad));
            a0 = fmaf(w, bfLo(rw0), a0);
            a1 = fmaf(w, bfHi(rw0), a1);
            den += w;
            rw0 = rw1; rw1 = rw2; rw2 = rw3;
            rw3 = (j + 4 <= cnt && l < 21) ? rec2[(size_t)srt[st + j + 3] * 24 + l] : 0u;
        }
        float v0 = (l < 20) ? a0 / den + bb0 : -3.4e38f;
        float v1 = (l < 20) ? a1 / den + bb1 : -3.4e38f;
        float mx = fmaxf(v0, v1);
        #pragma unroll
        for (int k = 16; k >= 1; k >>= 1) mx = fmaxf(mx, __shfl_xor(mx, k, 32));
        float ex = (l < 20) ? __expf(v0 - mx) + __expf(v1 - mx) : 0.f;
        #pragma unroll
        for (int k = 16; k >= 1; k >>= 1) ex += __shfl_xor(ex, k, 32);
        float lse = mx + logf(ex);
        if (l < 20)
            ((float2*)(out + (size_t)node * 40))[l] = make_float2(v0 - lse, v1 - lse);
    }
}

extern "C" void kernel_launch(void* const* d_in, const int* in_sizes, int n_in,
                              void* d_out, int out_size, void* d_ws, size_t ws_size,
                              hipStream_t stream) {
    const float* x      = (const float*)d_in[0];
    const int*   e1_src = (const int*)d_in[1];
    const int*   e1_dst = (const int*)d_in[2];
    const int*   e2_src = (const int*)d_in[3];
    const int*   e2_dst = (const int*)d_in[4];
    const float* W1s    = (const float*)d_in[5];
    const float* W1d    = (const float*)d_in[6];
    const float* att1s  = (const float*)d_in[7];
    const float* att1d  = (const float*)d_in[8];
    const float* b1     = (const float*)d_in[9];
    const float* W2s    = (const float*)d_in[10];
    const float* W2d    = (const float*)d_in[11];
    const float* att2s  = (const float*)d_in[12];
    const float* att2d  = (const float*)d_in[13];
    const float* b2     = (const float*)d_in[14];
    float* out = (float*)d_out;

    // ---- workspace layout (4-byte words) ----
    float* wsbase = (float*)d_ws;
    size_t o = 0;
    int*      gcnt1 = (int*)(wsbase + o);      o += NB1;
    int*      gcnt2 = (int*)(wsbase + o);      o += NB2;
    const size_t zeroWords = o;                // only counters need zeroing
    unsigned* bin1  = (unsigned*)(wsbase + o); o += (size_t)NB1 * CAPB1;
    unsigned* bin2  = (unsigned*)(wsbase + o); o += (size_t)NB2 * CAPB2;
    unsigned* rec1  = (unsigned*)(wsbase + o); o += (size_t)N0 * 16;
    float*    a_d1  = (float*)(wsbase + o);    o += (size_t)N1 * 2;
    unsigned* rec2  = (unsigned*)(wsbase + o); o += (size_t)N1 * 24;

    hipMemsetAsync(d_ws, 0, zeroWords * sizeof(float), stream);

    k1_kernel<<<NT1 + NT2 + BPJ, 256, 0, stream>>>(
        x, W1s, W1d, att1s, att1d, e1_src, e1_dst, e2_src, e2_dst,
        rec1, a_d1, gcnt1, bin1, gcnt2, bin2);

    k2_kernel<<<NB1, 512, 0, stream>>>(gcnt1, bin1, rec1, a_d1, b1,
                                       W2s, W2d, att2s, att2d, rec2);

    k3_kernel<<<NB2, 1024, 0, stream>>>(gcnt2, bin2, rec2, b2, out);
}